// Round 9
// baseline (364.874 us; speedup 1.0000x reference)
//
#include <hip/hip_runtime.h>

#define FEAT 128
#define BN_EPS 1e-5f
#define SUB 4        // sub-counters per node (virtual rows)
#define SUBSTRIDE 4  // uints between sub-counters (16B) -> one 64B line per node

typedef __attribute__((ext_vector_type(8))) short s8frag;
typedef __attribute__((ext_vector_type(4))) float f4frag;

union FragU { uint4 u; s8frag v; };

__device__ __forceinline__ unsigned short f2bf(float f) {
    unsigned u = __float_as_uint(f);
    unsigned r = (u + 0x7fffu + ((u >> 16) & 1u)) >> 16;
    return (unsigned short)r;
}
__device__ __forceinline__ void unpack2(unsigned d, float& lo, float& hi) {
    lo = __uint_as_float(d << 16);
    hi = __uint_as_float(d & 0xffff0000u);
}
__device__ __forceinline__ void acc8(float* acc, uint4 d) {
    float l, h;
    unpack2(d.x, l, h); acc[0] += l; acc[1] += h;
    unpack2(d.y, l, h); acc[2] += l; acc[3] += h;
    unpack2(d.z, l, h); acc[4] += l; acc[5] += h;
    unpack2(d.w, l, h); acc[6] += l; acc[7] += h;
}

// ---------------- prep: bf16 weights + BN constants --------------------------
__global__ void prep_all(const float* __restrict__ W1l, const float* __restrict__ W1r,
                         const float* __restrict__ W2l, const float* __restrict__ W2r,
                         const float* __restrict__ b1, const float* __restrict__ g,
                         const float* __restrict__ bt, const float* __restrict__ mu,
                         const float* __restrict__ var, const float* __restrict__ b2,
                         unsigned short* __restrict__ Wb1, unsigned short* __restrict__ Wb2,
                         float* __restrict__ bnsc, float* __restrict__ bnsh,
                         float* __restrict__ cb2) {
    int tid = blockIdx.x * blockDim.x + threadIdx.x;
    if (tid < 128 * 256) {
        int n = tid >> 8, k = tid & 255;
        float w = (k < 128) ? W1l[n * 128 + k] : W1r[n * 128 + (k - 128)];
        Wb1[tid] = f2bf(w);
    }
    if (tid < 128 * 128) {
        int n = tid >> 7, k = tid & 127;
        float w = (n < 64) ? W2l[n * 128 + k] : W2r[(n - 64) * 128 + k];
        Wb2[tid] = f2bf(w);
    }
    if (tid < 128) {
        float sc = rsqrtf(var[tid] + BN_EPS) * g[tid];
        bnsc[tid] = sc;
        bnsh[tid] = sc * (b1[tid] - mu[tid]) + bt[tid];
        cb2[tid] = (tid < 64) ? 0.f : b2[tid - 64];
    }
}

// ---------------- x -> bf16 (8 elems/thread) ---------------------------------
__global__ void convert_x(const float* __restrict__ x, unsigned short* __restrict__ xb,
                          long long total8) {
    long long t = (long long)blockIdx.x * blockDim.x + threadIdx.x;
    if (t >= total8) return;
    const float4* src = (const float4*)(x) + t * 2;
    float4 a = src[0], b = src[1];
    uint4 o;
    o.x = f2bf(a.x) | ((unsigned)f2bf(a.y) << 16);
    o.y = f2bf(a.z) | ((unsigned)f2bf(a.w) << 16);
    o.z = f2bf(b.x) | ((unsigned)f2bf(b.y) << 16);
    o.w = f2bf(b.z) | ((unsigned)f2bf(b.w) << 16);
    ((uint4*)xb)[t] = o;
}

// ---------------- degree count + per-edge rank over virtual rows -------------
// vrow = dst*SUB + (e & 3); counter at degc[vrow*SUBSTRIDE]
__global__ void count_rank(const int* __restrict__ dst, int E,
                           unsigned* __restrict__ degc, unsigned* __restrict__ rank) {
    int base = (blockIdx.x * blockDim.x + threadIdx.x) * 8;
    if (base + 8 <= E) {
        int4 d0 = *(const int4*)(dst + base);
        int4 d1 = *(const int4*)(dst + base + 4);
        unsigned r0 = atomicAdd(&degc[((size_t)d0.x * SUB + 0) * SUBSTRIDE], 1u);
        unsigned r1 = atomicAdd(&degc[((size_t)d0.y * SUB + 1) * SUBSTRIDE], 1u);
        unsigned r2 = atomicAdd(&degc[((size_t)d0.z * SUB + 2) * SUBSTRIDE], 1u);
        unsigned r3 = atomicAdd(&degc[((size_t)d0.w * SUB + 3) * SUBSTRIDE], 1u);
        unsigned r4 = atomicAdd(&degc[((size_t)d1.x * SUB + 0) * SUBSTRIDE], 1u);
        unsigned r5 = atomicAdd(&degc[((size_t)d1.y * SUB + 1) * SUBSTRIDE], 1u);
        unsigned r6 = atomicAdd(&degc[((size_t)d1.z * SUB + 2) * SUBSTRIDE], 1u);
        unsigned r7 = atomicAdd(&degc[((size_t)d1.w * SUB + 3) * SUBSTRIDE], 1u);
        *(uint4*)(rank + base)     = make_uint4(r0, r1, r2, r3);
        *(uint4*)(rank + base + 4) = make_uint4(r4, r5, r6, r7);
    } else {
        for (int e = base; e < E; e++)
            rank[e] = atomicAdd(&degc[((size_t)dst[e] * SUB + (e & 3)) * SUBSTRIDE], 1u);
    }
}

// ---------------- scan over M=4N virtual rows: 512 elems/block ---------------
__global__ void scan_block(const unsigned* __restrict__ degc, unsigned* __restrict__ excl,
                           unsigned* __restrict__ partials, int M) {
    __shared__ unsigned buf[256];
    int base = blockIdx.x * 512 + threadIdx.x * 2;
    unsigned v0 = (base < M) ? degc[(size_t)base * SUBSTRIDE] : 0u;
    unsigned v1 = (base + 1 < M) ? degc[(size_t)(base + 1) * SUBSTRIDE] : 0u;
    unsigned s = v0 + v1;
    buf[threadIdx.x] = s;
    __syncthreads();
    for (int off = 1; off < 256; off <<= 1) {
        unsigned t = (threadIdx.x >= (unsigned)off) ? buf[threadIdx.x - off] : 0u;
        __syncthreads();
        buf[threadIdx.x] += t;
        __syncthreads();
    }
    unsigned e = buf[threadIdx.x] - s;
    if (base < M) excl[base] = e;
    if (base + 1 < M) excl[base + 1] = e + v0;
    if (threadIdx.x == 255) partials[blockIdx.x] = buf[255];
}

__global__ void scan_partials(unsigned* __restrict__ partials, int nb) {
    __shared__ unsigned buf[1024];
    unsigned v = ((int)threadIdx.x < nb) ? partials[threadIdx.x] : 0u;
    buf[threadIdx.x] = v;
    __syncthreads();
    for (int off = 1; off < 1024; off <<= 1) {
        unsigned t = (threadIdx.x >= (unsigned)off) ? buf[threadIdx.x - off] : 0u;
        __syncthreads();
        buf[threadIdx.x] += t;
        __syncthreads();
    }
    if ((int)threadIdx.x < nb) partials[threadIdx.x] = buf[threadIdx.x] - v;
}

__global__ void scan_finish(unsigned* __restrict__ row_start,
                            const unsigned* __restrict__ partials, int M, int E) {
    int i = blockIdx.x * blockDim.x + threadIdx.x;
    if (i < M) row_start[i] = row_start[i] + partials[i >> 9];
    if (i == 0) row_start[M] = (unsigned)E;
}

// ---------------- CSR fill: atomic-free, 4 edges/thread ----------------------
__global__ void fill_csr(const int* __restrict__ src, const int* __restrict__ dst, int E,
                         const unsigned* __restrict__ row_start,
                         const unsigned* __restrict__ rank,
                         unsigned* __restrict__ csr_src) {
    int base = (blockIdx.x * blockDim.x + threadIdx.x) * 4;
    if (base + 4 <= E) {
        int4 d = *(const int4*)(dst + base);
        int4 s = *(const int4*)(src + base);
        uint4 r = *(const uint4*)(rank + base);
        unsigned p0 = row_start[(size_t)d.x * SUB + 0] + r.x;
        unsigned p1 = row_start[(size_t)d.y * SUB + 1] + r.y;
        unsigned p2 = row_start[(size_t)d.z * SUB + 2] + r.z;
        unsigned p3 = row_start[(size_t)d.w * SUB + 3] + r.w;
        csr_src[p0] = (unsigned)s.x;
        csr_src[p1] = (unsigned)s.y;
        csr_src[p2] = (unsigned)s.z;
        csr_src[p3] = (unsigned)s.w;
    } else {
        for (int e = base; e < E; e++)
            csr_src[row_start[(size_t)dst[e] * SUB + (e & 3)] + rank[e]] = (unsigned)src[e];
    }
}

// ---------------- gather + mean over 128 bf16 feats: 16 lanes/node, unroll 4 -
__global__ __launch_bounds__(256) void gather_mean_bf(const unsigned short* __restrict__ xb,
                                                      const unsigned* __restrict__ row_start,
                                                      const unsigned* __restrict__ csr_src,
                                                      unsigned short* __restrict__ aggb, int N) {
    int gid = blockIdx.x * 256 + threadIdx.x;
    int node = gid >> 4;
    if (node >= N) return;
    int f = (threadIdx.x & 15) * 8;
    unsigned s0 = row_start[(size_t)node * SUB];
    unsigned s1 = row_start[(size_t)node * SUB + SUB];
    float acc[8];
#pragma unroll
    for (int i = 0; i < 8; i++) acc[i] = 0.f;
    unsigned i = s0;
    for (; i + 4 <= s1; i += 4) {
        unsigned sa = csr_src[i], sb = csr_src[i + 1];
        unsigned sc = csr_src[i + 2], sd = csr_src[i + 3];
        uint4 da = *(const uint4*)(xb + (size_t)sa * 128 + f);
        uint4 db = *(const uint4*)(xb + (size_t)sb * 128 + f);
        uint4 dc = *(const uint4*)(xb + (size_t)sc * 128 + f);
        uint4 dd = *(const uint4*)(xb + (size_t)sd * 128 + f);
        acc8(acc, da); acc8(acc, db); acc8(acc, dc); acc8(acc, dd);
    }
    for (; i < s1; i++) {
        unsigned sa = csr_src[i];
        uint4 da = *(const uint4*)(xb + (size_t)sa * 128 + f);
        acc8(acc, da);
    }
    float inv = (s1 > s0) ? 1.0f / (float)(s1 - s0) : 0.f;
    uint4 o;
    o.x = f2bf(acc[0] * inv) | ((unsigned)f2bf(acc[1] * inv) << 16);
    o.y = f2bf(acc[2] * inv) | ((unsigned)f2bf(acc[3] * inv) << 16);
    o.z = f2bf(acc[4] * inv) | ((unsigned)f2bf(acc[5] * inv) << 16);
    o.w = f2bf(acc[6] * inv) | ((unsigned)f2bf(acc[7] * inv) << 16);
    *(uint4*)(aggb + (size_t)node * 128 + f) = o;
}

// ---------------- dense: layer1 GEMM+BN/ReLU + layer2 GEMM, LDS weights ------
__global__ __launch_bounds__(256) void sage_dense(
    const unsigned short* __restrict__ aggb,
    const unsigned short* __restrict__ xb,
    const unsigned short* __restrict__ Wb1,   // [128][256]
    const unsigned short* __restrict__ Wb2,   // [128][128]
    const float* __restrict__ bnsc, const float* __restrict__ bnsh,
    const float* __restrict__ cb2,
    unsigned short* __restrict__ uvb, int N)
{
    __shared__ __align__(16) unsigned short As[64 * 128];   // 16 KB (h transpose)
    __shared__ __align__(16) unsigned short Bs[128 * 128];  // 32 KB
    uint4* AsV = (uint4*)As;
    uint4* BsV = (uint4*)Bs;

    const int tid = threadIdx.x;
    const int wave = tid >> 6;
    const int lane = tid & 63;
    const int mr = lane & 15;
    const int q = lane >> 4;
    const int m0 = blockIdx.x * 64;
    const int mw = m0 + wave * 16 + mr;
    const bool mv = mw < N;

    FragU ag[4], ax[4];
#pragma unroll
    for (int kc4 = 0; kc4 < 4; kc4++) {
        ag[kc4].u = make_uint4(0u, 0u, 0u, 0u);
        ax[kc4].u = make_uint4(0u, 0u, 0u, 0u);
        if (mv) {
            ag[kc4].u = *(const uint4*)(aggb + (size_t)mw * 128 + kc4 * 32 + q * 8);
            ax[kc4].u = *(const uint4*)(xb + (size_t)mw * 128 + kc4 * 32 + q * 8);
        }
    }

#pragma unroll
    for (int i = 0; i < 8; i++) {
        int gch = tid + i * 256;
        int n = gch >> 4, c = gch & 15;
        BsV[n * 16 + (c ^ (n & 15))] = *(const uint4*)(Wb1 + (size_t)n * 256 + c * 8);
    }
    __syncthreads();

    f4frag acc[8];
#pragma unroll
    for (int j = 0; j < 8; j++)
#pragma unroll
        for (int r = 0; r < 4; r++) acc[j][r] = 0.f;

#pragma unroll
    for (int kc4 = 0; kc4 < 4; kc4++) {
#pragma unroll
        for (int j = 0; j < 8; j++) {
            FragU b;
            b.u = BsV[(j * 16 + mr) * 16 + ((kc4 * 4 + q) ^ mr)];
            acc[j] = __builtin_amdgcn_mfma_f32_16x16x32_bf16(ag[kc4].v, b.v, acc[j], 0, 0, 0);
        }
    }
    __syncthreads();

#pragma unroll
    for (int i = 0; i < 8; i++) {
        int gch = tid + i * 256;
        int n = gch >> 4, c = gch & 15;
        BsV[n * 16 + (c ^ (n & 15))] = *(const uint4*)(Wb1 + (size_t)n * 256 + 128 + c * 8);
    }
    __syncthreads();

#pragma unroll
    for (int kc4 = 0; kc4 < 4; kc4++) {
#pragma unroll
        for (int j = 0; j < 8; j++) {
            FragU b;
            b.u = BsV[(j * 16 + mr) * 16 + ((kc4 * 4 + q) ^ mr)];
            acc[j] = __builtin_amdgcn_mfma_f32_16x16x32_bf16(ax[kc4].v, b.v, acc[j], 0, 0, 0);
        }
    }

#pragma unroll
    for (int j = 0; j < 8; j++) {
        int n = j * 16 + mr;
        float sc = bnsc[n], sh = bnsh[n];
        int cn = n >> 3;
#pragma unroll
        for (int r = 0; r < 4; r++) {
            int ml = wave * 16 + q * 4 + r;
            float v = fmaxf(acc[j][r] * sc + sh, 0.f);
            As[(ml * 16 + (cn ^ (ml & 15))) * 8 + (n & 7)] = f2bf(v);
        }
    }
    __syncthreads();

#pragma unroll
    for (int i = 0; i < 8; i++) {
        int gch = tid + i * 256;
        int n = gch >> 4, c = gch & 15;
        BsV[n * 16 + (c ^ (n & 15))] = *(const uint4*)(Wb2 + (size_t)n * 128 + c * 8);
    }
    __syncthreads();

#pragma unroll
    for (int j = 0; j < 8; j++)
#pragma unroll
        for (int r = 0; r < 4; r++) acc[j][r] = 0.f;
    const int arow = (wave * 16 + mr) * 16;
#pragma unroll
    for (int kc4 = 0; kc4 < 4; kc4++) {
        FragU a;
        a.u = AsV[arow + ((kc4 * 4 + q) ^ mr)];
#pragma unroll
        for (int j = 0; j < 8; j++) {
            FragU b;
            b.u = BsV[(j * 16 + mr) * 16 + ((kc4 * 4 + q) ^ mr)];
            acc[j] = __builtin_amdgcn_mfma_f32_16x16x32_bf16(a.v, b.v, acc[j], 0, 0, 0);
        }
    }

#pragma unroll
    for (int j = 0; j < 8; j++) {
        int n = j * 16 + mr;
        float cb = cb2[n];
#pragma unroll
        for (int r = 0; r < 4; r++) {
            int mrow = m0 + wave * 16 + q * 4 + r;
            if (mrow < N)
                uvb[(size_t)mrow * 128 + n] = f2bf(acc[j][r] + cb);
        }
    }
}

// ---------------- layer-2 finish: out = mean_agg(u) + v, fp32, unroll 4 ------
__global__ __launch_bounds__(256) void gather_out_bf(const unsigned short* __restrict__ uvb,
                                                     const unsigned* __restrict__ row_start,
                                                     const unsigned* __restrict__ csr_src,
                                                     float* __restrict__ out, int N) {
    int gid = blockIdx.x * 256 + threadIdx.x;
    int node = gid >> 3;
    if (node >= N) return;
    int f = (threadIdx.x & 7) * 8;
    unsigned s0 = row_start[(size_t)node * SUB];
    unsigned s1 = row_start[(size_t)node * SUB + SUB];
    float acc[8];
#pragma unroll
    for (int i = 0; i < 8; i++) acc[i] = 0.f;
    unsigned i = s0;
    for (; i + 4 <= s1; i += 4) {
        unsigned sa = csr_src[i], sb = csr_src[i + 1];
        unsigned sc = csr_src[i + 2], sd = csr_src[i + 3];
        uint4 da = *(const uint4*)(uvb + (size_t)sa * 128 + f);
        uint4 db = *(const uint4*)(uvb + (size_t)sb * 128 + f);
        uint4 dc = *(const uint4*)(uvb + (size_t)sc * 128 + f);
        uint4 dd = *(const uint4*)(uvb + (size_t)sd * 128 + f);
        acc8(acc, da); acc8(acc, db); acc8(acc, dc); acc8(acc, dd);
    }
    for (; i < s1; i++) {
        unsigned sa = csr_src[i];
        uint4 da = *(const uint4*)(uvb + (size_t)sa * 128 + f);
        acc8(acc, da);
    }
    float inv = (s1 > s0) ? 1.0f / (float)(s1 - s0) : 0.f;
    uint4 dv = *(const uint4*)(uvb + (size_t)node * 128 + 64 + f);
    float vv[8];
    unpack2(dv.x, vv[0], vv[1]);
    unpack2(dv.y, vv[2], vv[3]);
    unpack2(dv.z, vv[4], vv[5]);
    unpack2(dv.w, vv[6], vv[7]);
    float4 o0 = make_float4(acc[0] * inv + vv[0], acc[1] * inv + vv[1],
                            acc[2] * inv + vv[2], acc[3] * inv + vv[3]);
    float4 o1 = make_float4(acc[4] * inv + vv[4], acc[5] * inv + vv[5],
                            acc[6] * inv + vv[6], acc[7] * inv + vv[7]);
    *(float4*)(out + (size_t)node * 64 + f) = o0;
    *(float4*)(out + (size_t)node * 64 + f + 4) = o1;
}

extern "C" void kernel_launch(void* const* d_in, const int* in_sizes, int n_in,
                              void* d_out, int out_size, void* d_ws, size_t ws_size,
                              hipStream_t stream) {
    const float* x     = (const float*)d_in[0];
    const int*   edge  = (const int*)d_in[1];
    const float* W1l   = (const float*)d_in[2];
    const float* b1    = (const float*)d_in[3];
    const float* W1r   = (const float*)d_in[4];
    const float* gamma = (const float*)d_in[5];
    const float* beta  = (const float*)d_in[6];
    const float* mean  = (const float*)d_in[7];
    const float* var   = (const float*)d_in[8];
    const float* W2l   = (const float*)d_in[9];
    const float* b2    = (const float*)d_in[10];
    const float* W2r   = (const float*)d_in[11];

    const int N = in_sizes[0] / FEAT;
    const int E = in_sizes[1] / 2;
    const int M = N * SUB;           // virtual rows
    const int* srcI = edge;
    const int* dstI = edge + E;

    unsigned short* uvb  = (unsigned short*)d_ws;      // N*128
    unsigned short* aggb = uvb + (size_t)N * 128;      // N*128
    unsigned short* xb   = aggb + (size_t)N * 128;     // N*128
    unsigned short* Wb1  = xb + (size_t)N * 128;       // 128*256
    unsigned short* Wb2  = Wb1 + 256 * 128;            // 128*128
    float* bnsc = (float*)(Wb2 + 128 * 128);           // 128
    float* bnsh = bnsc + 128;                          // 128
    float* cb2  = bnsh + 128;                          // 128
    unsigned* degc      = (unsigned*)(cb2 + 128);      // M*SUBSTRIDE
    unsigned* row_start = degc + (size_t)M * SUBSTRIDE;// M+1
    unsigned* rank      = row_start + (M + 1);         // E
    unsigned* partials  = rank + E;                    // 1024
    unsigned* csr_src   = partials + 1024;             // E

    float* outp = (float*)d_out;
    const int nb = (M + 511) / 512;  // 782 for N=100k

    hipMemsetAsync(degc, 0, (size_t)M * SUBSTRIDE * sizeof(unsigned), stream);

    prep_all<<<128, 256, 0, stream>>>(W1l, W1r, W2l, W2r, b1, gamma, beta, mean, var, b2,
                                      Wb1, Wb2, bnsc, bnsh, cb2);
    {
        long long total8 = (long long)N * 128 / 8;
        convert_x<<<(int)((total8 + 255) / 256), 256, 0, stream>>>(x, xb, total8);
    }
    {
        int threads8 = (E + 7) / 8;
        count_rank<<<(threads8 + 255) / 256, 256, 0, stream>>>(dstI, E, degc, rank);
    }
    scan_block<<<nb, 256, 0, stream>>>(degc, row_start, partials, M);
    scan_partials<<<1, 1024, 0, stream>>>(partials, nb);
    scan_finish<<<(M + 255) / 256, 256, 0, stream>>>(row_start, partials, M, E);
    {
        int threads4 = (E + 3) / 4;
        fill_csr<<<(threads4 + 255) / 256, 256, 0, stream>>>(srcI, dstI, E, row_start, rank, csr_src);
    }

    gather_mean_bf<<<(N * 16 + 255) / 256, 256, 0, stream>>>(xb, row_start, csr_src, aggb, N);
    sage_dense<<<(N + 63) / 64, 256, 0, stream>>>(aggb, xb, Wb1, Wb2, bnsc, bnsh, cb2, uvb, N);
    gather_out_bf<<<(N * 8 + 255) / 256, 256, 0, stream>>>(uvb, row_start, csr_src, outp, N);
}

// Round 10
// 335.041 us; speedup vs baseline: 1.0890x; 1.0890x over previous
//
#include <hip/hip_runtime.h>

#define FEAT 128
#define BN_EPS 1e-5f
#define CSTRIDE 16   // one degree counter per 64B line

typedef __attribute__((ext_vector_type(8))) short s8frag;
typedef __attribute__((ext_vector_type(4))) float f4frag;

union FragU { uint4 u; s8frag v; };

__device__ __forceinline__ unsigned short f2bf(float f) {
    unsigned u = __float_as_uint(f);
    unsigned r = (u + 0x7fffu + ((u >> 16) & 1u)) >> 16;
    return (unsigned short)r;
}
__device__ __forceinline__ void unpack2(unsigned d, float& lo, float& hi) {
    lo = __uint_as_float(d << 16);
    hi = __uint_as_float(d & 0xffff0000u);
}
__device__ __forceinline__ void acc8(float* acc, uint4 d) {
    float l, h;
    unpack2(d.x, l, h); acc[0] += l; acc[1] += h;
    unpack2(d.y, l, h); acc[2] += l; acc[3] += h;
    unpack2(d.z, l, h); acc[4] += l; acc[5] += h;
    unpack2(d.w, l, h); acc[6] += l; acc[7] += h;
}

// ---------------- FRONT: count+rank (section A) | x->bf16 (B) | weight prep (C)
// Section A first so its latency-bound blocks are resident immediately;
// B/C's BW-bound work overlaps under A's atomic latency.
__global__ __launch_bounds__(256) void front_kernel(
    const int* __restrict__ dst, int E, int Tc,
    unsigned* __restrict__ degc, unsigned char* __restrict__ rank8,
    const float* __restrict__ x, unsigned short* __restrict__ xb, int total8,
    const float* __restrict__ W1l, const float* __restrict__ W1r,
    const float* __restrict__ W2l, const float* __restrict__ W2r,
    const float* __restrict__ b1, const float* __restrict__ g,
    const float* __restrict__ bt, const float* __restrict__ mu,
    const float* __restrict__ var, const float* __restrict__ b2,
    unsigned short* __restrict__ Wb1, unsigned short* __restrict__ Wb2,
    float* __restrict__ bnsc, float* __restrict__ bnsh, float* __restrict__ cb2)
{
    int tid = blockIdx.x * 256 + threadIdx.x;
    if (tid < Tc) {
        // ---- count + rank: 8 edges/thread, byte-packed ranks ----
        int base = tid * 8;
        if (base + 8 <= E) {
            int4 d0 = *(const int4*)(dst + base);
            int4 d1 = *(const int4*)(dst + base + 4);
            unsigned r0 = atomicAdd(&degc[(size_t)d0.x * CSTRIDE], 1u);
            unsigned r1 = atomicAdd(&degc[(size_t)d0.y * CSTRIDE], 1u);
            unsigned r2 = atomicAdd(&degc[(size_t)d0.z * CSTRIDE], 1u);
            unsigned r3 = atomicAdd(&degc[(size_t)d0.w * CSTRIDE], 1u);
            unsigned r4 = atomicAdd(&degc[(size_t)d1.x * CSTRIDE], 1u);
            unsigned r5 = atomicAdd(&degc[(size_t)d1.y * CSTRIDE], 1u);
            unsigned r6 = atomicAdd(&degc[(size_t)d1.z * CSTRIDE], 1u);
            unsigned r7 = atomicAdd(&degc[(size_t)d1.w * CSTRIDE], 1u);
            unsigned p0 = (r0 & 255u) | ((r1 & 255u) << 8) | ((r2 & 255u) << 16) | ((r3 & 255u) << 24);
            unsigned p1 = (r4 & 255u) | ((r5 & 255u) << 8) | ((r6 & 255u) << 16) | ((r7 & 255u) << 24);
            ((unsigned*)rank8)[tid * 2]     = p0;
            ((unsigned*)rank8)[tid * 2 + 1] = p1;
        } else {
            for (int e = base; e < E; e++)
                rank8[e] = (unsigned char)atomicAdd(&degc[(size_t)dst[e] * CSTRIDE], 1u);
        }
    } else if (tid < Tc + total8) {
        // ---- convert x -> bf16 (8 elems/thread) ----
        int t = tid - Tc;
        const float4* src = (const float4*)(x) + (size_t)t * 2;
        float4 a = src[0], b = src[1];
        uint4 o;
        o.x = f2bf(a.x) | ((unsigned)f2bf(a.y) << 16);
        o.y = f2bf(a.z) | ((unsigned)f2bf(a.w) << 16);
        o.z = f2bf(b.x) | ((unsigned)f2bf(b.y) << 16);
        o.w = f2bf(b.z) | ((unsigned)f2bf(b.w) << 16);
        ((uint4*)xb)[t] = o;
    } else {
        // ---- weight prep + BN constants ----
        int idx = tid - Tc - total8;
        if (idx < 128 * 256) {
            int n = idx >> 8, k = idx & 255;
            float w = (k < 128) ? W1l[n * 128 + k] : W1r[n * 128 + (k - 128)];
            Wb1[idx] = f2bf(w);
        }
        if (idx < 128 * 128) {
            int n = idx >> 7, k = idx & 127;
            float w = (n < 64) ? W2l[n * 128 + k] : W2r[(n - 64) * 128 + k];
            Wb2[idx] = f2bf(w);
        }
        if (idx < 128) {
            float sc = rsqrtf(var[idx] + BN_EPS) * g[idx];
            bnsc[idx] = sc;
            bnsh[idx] = sc * (b1[idx] - mu[idx]) + bt[idx];
            cb2[idx] = (idx < 64) ? 0.f : b2[idx - 64];
        }
    }
}

// ---------------- per-block exclusive scan over padded degc ------------------
__global__ void scan_block(const unsigned* __restrict__ degc, unsigned* __restrict__ excl,
                           unsigned* __restrict__ partials, int N) {
    __shared__ unsigned buf[256];
    int i = blockIdx.x * 256 + threadIdx.x;
    unsigned v = (i < N) ? degc[(size_t)i * CSTRIDE] : 0u;
    buf[threadIdx.x] = v;
    __syncthreads();
    for (int off = 1; off < 256; off <<= 1) {
        unsigned t = (threadIdx.x >= (unsigned)off) ? buf[threadIdx.x - off] : 0u;
        __syncthreads();
        buf[threadIdx.x] += t;
        __syncthreads();
    }
    if (i < N) excl[i] = buf[threadIdx.x] - v;
    if (threadIdx.x == 255) partials[blockIdx.x] = buf[255];
}

// ---------------- finish: each block reduces partials[0..b-1] itself ---------
__global__ void scan_finish(unsigned* __restrict__ row_start,
                            const unsigned* __restrict__ partials, int N, int E) {
    __shared__ unsigned red[256];
    int b = blockIdx.x;
    unsigned s = 0;
    for (int t = threadIdx.x; t < b; t += 256) s += partials[t];
    red[threadIdx.x] = s;
    __syncthreads();
    for (int off = 128; off > 0; off >>= 1) {
        if ((int)threadIdx.x < off) red[threadIdx.x] += red[threadIdx.x + off];
        __syncthreads();
    }
    unsigned base = red[0];
    int i = b * 256 + threadIdx.x;
    if (i < N) row_start[i] += base;
    if (i == 0) row_start[N] = (unsigned)E;
}

// ---------------- CSR fill: atomic-free, 4 edges/thread, byte ranks ----------
__global__ void fill_csr(const int* __restrict__ src, const int* __restrict__ dst, int E,
                         const unsigned* __restrict__ row_start,
                         const unsigned char* __restrict__ rank8,
                         unsigned* __restrict__ csr_src) {
    int base = (blockIdx.x * blockDim.x + threadIdx.x) * 4;
    if (base + 4 <= E) {
        int4 d = *(const int4*)(dst + base);
        int4 s = *(const int4*)(src + base);
        unsigned rp = ((const unsigned*)rank8)[base >> 2];
        unsigned p0 = row_start[d.x] + (rp & 255u);
        unsigned p1 = row_start[d.y] + ((rp >> 8) & 255u);
        unsigned p2 = row_start[d.z] + ((rp >> 16) & 255u);
        unsigned p3 = row_start[d.w] + ((rp >> 24) & 255u);
        csr_src[p0] = (unsigned)s.x;
        csr_src[p1] = (unsigned)s.y;
        csr_src[p2] = (unsigned)s.z;
        csr_src[p3] = (unsigned)s.w;
    } else {
        for (int e = base; e < E; e++)
            csr_src[row_start[dst[e]] + rank8[e]] = (unsigned)src[e];
    }
}

// ---------------- gather + mean over 128 bf16 feats: 16 lanes/node, unroll 4 -
__global__ __launch_bounds__(256) void gather_mean_bf(const unsigned short* __restrict__ xb,
                                                      const unsigned* __restrict__ row_start,
                                                      const unsigned* __restrict__ csr_src,
                                                      unsigned short* __restrict__ aggb, int N) {
    int gid = blockIdx.x * 256 + threadIdx.x;
    int node = gid >> 4;
    if (node >= N) return;
    int f = (threadIdx.x & 15) * 8;
    unsigned s0 = row_start[node], s1 = row_start[node + 1];
    float acc[8];
#pragma unroll
    for (int i = 0; i < 8; i++) acc[i] = 0.f;
    unsigned i = s0;
    for (; i + 4 <= s1; i += 4) {
        unsigned sa = csr_src[i], sb = csr_src[i + 1];
        unsigned sc = csr_src[i + 2], sd = csr_src[i + 3];
        uint4 da = *(const uint4*)(xb + (size_t)sa * 128 + f);
        uint4 db = *(const uint4*)(xb + (size_t)sb * 128 + f);
        uint4 dc = *(const uint4*)(xb + (size_t)sc * 128 + f);
        uint4 dd = *(const uint4*)(xb + (size_t)sd * 128 + f);
        acc8(acc, da); acc8(acc, db); acc8(acc, dc); acc8(acc, dd);
    }
    for (; i < s1; i++) {
        unsigned sa = csr_src[i];
        uint4 da = *(const uint4*)(xb + (size_t)sa * 128 + f);
        acc8(acc, da);
    }
    float inv = (s1 > s0) ? 1.0f / (float)(s1 - s0) : 0.f;
    uint4 o;
    o.x = f2bf(acc[0] * inv) | ((unsigned)f2bf(acc[1] * inv) << 16);
    o.y = f2bf(acc[2] * inv) | ((unsigned)f2bf(acc[3] * inv) << 16);
    o.z = f2bf(acc[4] * inv) | ((unsigned)f2bf(acc[5] * inv) << 16);
    o.w = f2bf(acc[6] * inv) | ((unsigned)f2bf(acc[7] * inv) << 16);
    *(uint4*)(aggb + (size_t)node * 128 + f) = o;
}

// ---------------- dense: layer1 GEMM+BN/ReLU + layer2 GEMM, LDS weights ------
__global__ __launch_bounds__(256) void sage_dense(
    const unsigned short* __restrict__ aggb,
    const unsigned short* __restrict__ xb,
    const unsigned short* __restrict__ Wb1,   // [128][256]
    const unsigned short* __restrict__ Wb2,   // [128][128]
    const float* __restrict__ bnsc, const float* __restrict__ bnsh,
    const float* __restrict__ cb2,
    unsigned short* __restrict__ uvb, int N)
{
    __shared__ __align__(16) unsigned short As[64 * 128];   // 16 KB (h transpose)
    __shared__ __align__(16) unsigned short Bs[128 * 128];  // 32 KB
    uint4* AsV = (uint4*)As;
    uint4* BsV = (uint4*)Bs;

    const int tid = threadIdx.x;
    const int wave = tid >> 6;
    const int lane = tid & 63;
    const int mr = lane & 15;
    const int q = lane >> 4;
    const int m0 = blockIdx.x * 64;
    const int mw = m0 + wave * 16 + mr;
    const bool mv = mw < N;

    FragU ag[4], ax[4];
#pragma unroll
    for (int kc4 = 0; kc4 < 4; kc4++) {
        ag[kc4].u = make_uint4(0u, 0u, 0u, 0u);
        ax[kc4].u = make_uint4(0u, 0u, 0u, 0u);
        if (mv) {
            ag[kc4].u = *(const uint4*)(aggb + (size_t)mw * 128 + kc4 * 32 + q * 8);
            ax[kc4].u = *(const uint4*)(xb + (size_t)mw * 128 + kc4 * 32 + q * 8);
        }
    }

#pragma unroll
    for (int i = 0; i < 8; i++) {
        int gch = tid + i * 256;
        int n = gch >> 4, c = gch & 15;
        BsV[n * 16 + (c ^ (n & 15))] = *(const uint4*)(Wb1 + (size_t)n * 256 + c * 8);
    }
    __syncthreads();

    f4frag acc[8];
#pragma unroll
    for (int j = 0; j < 8; j++)
#pragma unroll
        for (int r = 0; r < 4; r++) acc[j][r] = 0.f;

#pragma unroll
    for (int kc4 = 0; kc4 < 4; kc4++) {
#pragma unroll
        for (int j = 0; j < 8; j++) {
            FragU b;
            b.u = BsV[(j * 16 + mr) * 16 + ((kc4 * 4 + q) ^ mr)];
            acc[j] = __builtin_amdgcn_mfma_f32_16x16x32_bf16(ag[kc4].v, b.v, acc[j], 0, 0, 0);
        }
    }
    __syncthreads();

#pragma unroll
    for (int i = 0; i < 8; i++) {
        int gch = tid + i * 256;
        int n = gch >> 4, c = gch & 15;
        BsV[n * 16 + (c ^ (n & 15))] = *(const uint4*)(Wb1 + (size_t)n * 256 + 128 + c * 8);
    }
    __syncthreads();

#pragma unroll
    for (int kc4 = 0; kc4 < 4; kc4++) {
#pragma unroll
        for (int j = 0; j < 8; j++) {
            FragU b;
            b.u = BsV[(j * 16 + mr) * 16 + ((kc4 * 4 + q) ^ mr)];
            acc[j] = __builtin_amdgcn_mfma_f32_16x16x32_bf16(ax[kc4].v, b.v, acc[j], 0, 0, 0);
        }
    }

#pragma unroll
    for (int j = 0; j < 8; j++) {
        int n = j * 16 + mr;
        float sc = bnsc[n], sh = bnsh[n];
        int cn = n >> 3;
#pragma unroll
        for (int r = 0; r < 4; r++) {
            int ml = wave * 16 + q * 4 + r;
            float v = fmaxf(acc[j][r] * sc + sh, 0.f);
            As[(ml * 16 + (cn ^ (ml & 15))) * 8 + (n & 7)] = f2bf(v);
        }
    }
    __syncthreads();

#pragma unroll
    for (int i = 0; i < 8; i++) {
        int gch = tid + i * 256;
        int n = gch >> 4, c = gch & 15;
        BsV[n * 16 + (c ^ (n & 15))] = *(const uint4*)(Wb2 + (size_t)n * 128 + c * 8);
    }
    __syncthreads();

#pragma unroll
    for (int j = 0; j < 8; j++)
#pragma unroll
        for (int r = 0; r < 4; r++) acc[j][r] = 0.f;
    const int arow = (wave * 16 + mr) * 16;
#pragma unroll
    for (int kc4 = 0; kc4 < 4; kc4++) {
        FragU a;
        a.u = AsV[arow + ((kc4 * 4 + q) ^ mr)];
#pragma unroll
        for (int j = 0; j < 8; j++) {
            FragU b;
            b.u = BsV[(j * 16 + mr) * 16 + ((kc4 * 4 + q) ^ mr)];
            acc[j] = __builtin_amdgcn_mfma_f32_16x16x32_bf16(a.v, b.v, acc[j], 0, 0, 0);
        }
    }

#pragma unroll
    for (int j = 0; j < 8; j++) {
        int n = j * 16 + mr;
        float cb = cb2[n];
#pragma unroll
        for (int r = 0; r < 4; r++) {
            int mrow = m0 + wave * 16 + q * 4 + r;
            if (mrow < N)
                uvb[(size_t)mrow * 128 + n] = f2bf(acc[j][r] + cb);
        }
    }
}

// ---------------- layer-2 finish: out = mean_agg(u) + v, fp32, unroll 4 ------
__global__ __launch_bounds__(256) void gather_out_bf(const unsigned short* __restrict__ uvb,
                                                     const unsigned* __restrict__ row_start,
                                                     const unsigned* __restrict__ csr_src,
                                                     float* __restrict__ out, int N) {
    int gid = blockIdx.x * 256 + threadIdx.x;
    int node = gid >> 3;
    if (node >= N) return;
    int f = (threadIdx.x & 7) * 8;
    unsigned s0 = row_start[node], s1 = row_start[node + 1];
    float acc[8];
#pragma unroll
    for (int i = 0; i < 8; i++) acc[i] = 0.f;
    unsigned i = s0;
    for (; i + 4 <= s1; i += 4) {
        unsigned sa = csr_src[i], sb = csr_src[i + 1];
        unsigned sc = csr_src[i + 2], sd = csr_src[i + 3];
        uint4 da = *(const uint4*)(uvb + (size_t)sa * 128 + f);
        uint4 db = *(const uint4*)(uvb + (size_t)sb * 128 + f);
        uint4 dc = *(const uint4*)(uvb + (size_t)sc * 128 + f);
        uint4 dd = *(const uint4*)(uvb + (size_t)sd * 128 + f);
        acc8(acc, da); acc8(acc, db); acc8(acc, dc); acc8(acc, dd);
    }
    for (; i < s1; i++) {
        unsigned sa = csr_src[i];
        uint4 da = *(const uint4*)(uvb + (size_t)sa * 128 + f);
        acc8(acc, da);
    }
    float inv = (s1 > s0) ? 1.0f / (float)(s1 - s0) : 0.f;
    uint4 dv = *(const uint4*)(uvb + (size_t)node * 128 + 64 + f);
    float vv[8];
    unpack2(dv.x, vv[0], vv[1]);
    unpack2(dv.y, vv[2], vv[3]);
    unpack2(dv.z, vv[4], vv[5]);
    unpack2(dv.w, vv[6], vv[7]);
    float4 o0 = make_float4(acc[0] * inv + vv[0], acc[1] * inv + vv[1],
                            acc[2] * inv + vv[2], acc[3] * inv + vv[3]);
    float4 o1 = make_float4(acc[4] * inv + vv[4], acc[5] * inv + vv[5],
                            acc[6] * inv + vv[6], acc[7] * inv + vv[7]);
    *(float4*)(out + (size_t)node * 64 + f) = o0;
    *(float4*)(out + (size_t)node * 64 + f + 4) = o1;
}

extern "C" void kernel_launch(void* const* d_in, const int* in_sizes, int n_in,
                              void* d_out, int out_size, void* d_ws, size_t ws_size,
                              hipStream_t stream) {
    const float* x     = (const float*)d_in[0];
    const int*   edge  = (const int*)d_in[1];
    const float* W1l   = (const float*)d_in[2];
    const float* b1    = (const float*)d_in[3];
    const float* W1r   = (const float*)d_in[4];
    const float* gamma = (const float*)d_in[5];
    const float* beta  = (const float*)d_in[6];
    const float* mean  = (const float*)d_in[7];
    const float* var   = (const float*)d_in[8];
    const float* W2l   = (const float*)d_in[9];
    const float* b2    = (const float*)d_in[10];
    const float* W2r   = (const float*)d_in[11];

    const int N = in_sizes[0] / FEAT;
    const int E = in_sizes[1] / 2;
    const int* srcI = edge;
    const int* dstI = edge + E;

    unsigned short* uvb  = (unsigned short*)d_ws;      // N*128
    unsigned short* aggb = uvb + (size_t)N * 128;      // N*128
    unsigned short* xb   = aggb + (size_t)N * 128;     // N*128
    unsigned short* Wb1  = xb + (size_t)N * 128;       // 128*256
    unsigned short* Wb2  = Wb1 + 256 * 128;            // 128*128
    float* bnsc = (float*)(Wb2 + 128 * 128);           // 128
    float* bnsh = bnsc + 128;                          // 128
    float* cb2  = bnsh + 128;                          // 128
    unsigned* degc      = (unsigned*)(cb2 + 128);      // N*CSTRIDE
    unsigned* row_start = degc + (size_t)N * CSTRIDE;  // N+1
    unsigned* partials  = row_start + (N + 1);         // 1024
    unsigned char* rank8 = (unsigned char*)(partials + 1024);        // E bytes (4-aligned)
    unsigned* csr_src   = (unsigned*)(rank8 + ((E + 3) & ~3));       // E

    float* outp = (float*)d_out;
    const int nb = (N + 255) / 256;

    hipMemsetAsync(degc, 0, (size_t)N * CSTRIDE * sizeof(unsigned), stream);

    // front: count+rank | convert | prep, one dispatch
    {
        const int Tc = (E + 7) / 8;
        const int total8 = N * FEAT / 8;
        const int prepT = 128 * 256;
        const int threads = Tc + total8 + prepT;
        front_kernel<<<(threads + 255) / 256, 256, 0, stream>>>(
            dstI, E, Tc, degc, rank8, x, xb, total8,
            W1l, W1r, W2l, W2r, b1, gamma, beta, mean, var, b2,
            Wb1, Wb2, bnsc, bnsh, cb2);
    }
    scan_block<<<nb, 256, 0, stream>>>(degc, row_start, partials, N);
    scan_finish<<<nb, 256, 0, stream>>>(row_start, partials, N, E);
    {
        int threads4 = (E + 3) / 4;
        fill_csr<<<(threads4 + 255) / 256, 256, 0, stream>>>(srcI, dstI, E, row_start, rank8, csr_src);
    }

    gather_mean_bf<<<(N * 16 + 255) / 256, 256, 0, stream>>>(xb, row_start, csr_src, aggb, N);
    sage_dense<<<(N + 63) / 64, 256, 0, stream>>>(aggb, xb, Wb1, Wb2, bnsc, bnsh, cb2, uvb, N);
    gather_out_bf<<<(N * 8 + 255) / 256, 256, 0, stream>>>(uvb, row_start, csr_src, outp, N);
}